// Round 24
// baseline (73.117 us; speedup 1.0000x reference)
//
#include <hip/hip_runtime.h>
#include <hip/hip_bf16.h>
#include <hip/hip_fp16.h>

// SJLT projection: out[b, idx[d,c]] += x[b,d] * (2*sign[d,c]-1)
// B=64, D=262144, C=4, P=4096
//
// R24 = R23 with the transpose branch VECTORIZED (single change).
// R23 post-mortem: k_prep measured 38.7us at 1.96 TB/s (31% of achievable,
// VALU 15%) -- scalar f32 loads (4B/lane) + scalar ushort stores (2B/lane),
// Common-mistake #2 in our own kernel. Fix: float4 reads (16B/lane), LDS
// float tile[64][65] (2-way banks = free), f16 pack in regs, uint2 writes
// (8B/lane, d-rows contiguous). Floor ~100MB @ 5TB/s ~= 20us.
// k_process (batch-8 scalar-guarded, session-best ~26us), binpack branch,
// k_reduce: R23 verbatim.

constexpr int B_DIM = 64;
constexpr int D_DIM = 262144;
constexpr int P_DIM = 4096;

constexpr int NDS   = 64;
constexpr int SLICE = D_DIM / NDS;      // 4096
constexpr int NBIN  = 16;               // binpack bins (256-wide)
constexpr int NSC   = 16;               // scanners per dslice
constexpr int SC_D  = SLICE / NSC;      // 256
constexpr int BCAP  = 128;              // per (dslice,sc,bin): mean 64, 8 sigma
constexpr int NHB   = 32;               // half-bins (128-wide)
constexpr int WPB   = 8;
constexpr int PR_W  = 16;               // p-slots per wave
constexpr int NPR   = P_DIM / PR_W;     // 256
constexpr int LCAP  = 128;              // per-wave list: mean 64, 8 sigma

constexpr int TRANS_BLOCKS = D_DIM / 64;   // 4096
constexpr int BINPK_BLOCKS = NDS * 4;      // 256

// ---- ws layout ----
constexpr size_t REG_OFF   = 0;
constexpr size_t REG_BYTES = (size_t)NDS * NSC * NBIN * BCAP * 4;          // 8.4 MB
constexpr size_t CNT_OFF   = REG_OFF + REG_BYTES;
constexpr size_t CNT_BYTES = (size_t)NDS * NSC * NBIN * 4;                 // 64 KB
constexpr size_t XT_OFF    = CNT_OFF + CNT_BYTES;
constexpr size_t XT_BYTES  = (size_t)D_DIM * B_DIM * 2;                    // 33.5 MB
constexpr size_t PART_OFF  = XT_OFF + XT_BYTES;
constexpr size_t PART_BYTES = (size_t)NPR * NDS * PR_W * B_DIM * 2;        // 33.5 MB
constexpr size_t WS_NEED   = PART_OFF + PART_BYTES;                        // ~76 MB

// ---------------- K1: merged transpose (f16, vectorized) + binpack ----------
// binpack entry u32: bits 0-18 rowbyte (dloc-in-slice*128), 19-26 p&255,
//                    bit 31 = (sv^1) -> negate when set.
__global__ __launch_bounds__(256) void k_prep(
    const float* __restrict__ x,
    const int* __restrict__ idx, const int* __restrict__ sgn,
    unsigned short* __restrict__ xTh,
    unsigned* __restrict__ reg, int* __restrict__ cnt) {
    __shared__ float tile[64 * 65];
    const int t = threadIdx.x;
    const int lane = t & 63;

    if (blockIdx.x < TRANS_BLOCKS) {
        // ---- transpose x[64][D] -> xTh[D][64] (f16), vectorized ----
        const int d0 = blockIdx.x * 64;
        // phase 1: float4 reads (16B/lane); tile[d][b], stride 65 (2-way banks)
        #pragma unroll
        for (int i = 0; i < 4; ++i) {
            const int flat = i * 256 + t;          // 0..1023
            const int b = flat >> 4;               // 0..63
            const int c = flat & 15;               // float4 col
            const float4 v = *reinterpret_cast<const float4*>(
                x + (size_t)b * D_DIM + d0 + c * 4);
            tile[(c * 4 + 0) * 65 + b] = v.x;
            tile[(c * 4 + 1) * 65 + b] = v.y;
            tile[(c * 4 + 2) * 65 + b] = v.z;
            tile[(c * 4 + 3) * 65 + b] = v.w;
        }
        __syncthreads();
        // phase 2: pack 4 b's into 2 dwords, uint2 store (8B/lane, contiguous)
        unsigned* xTh32 = reinterpret_cast<unsigned*>(xTh);
        #pragma unroll
        for (int i = 0; i < 4; ++i) {
            const int flat = i * 256 + t;          // 0..1023
            const int d  = flat >> 4;              // 0..63
            const int jj = flat & 15;              // uint2 col (4 b's)
            const float f0 = tile[d * 65 + jj * 4 + 0];
            const float f1 = tile[d * 65 + jj * 4 + 1];
            const float f2 = tile[d * 65 + jj * 4 + 2];
            const float f3 = tile[d * 65 + jj * 4 + 3];
            const unsigned short h0 = __builtin_bit_cast(unsigned short, __float2half_rn(f0));
            const unsigned short h1 = __builtin_bit_cast(unsigned short, __float2half_rn(f1));
            const unsigned short h2 = __builtin_bit_cast(unsigned short, __float2half_rn(f2));
            const unsigned short h3 = __builtin_bit_cast(unsigned short, __float2half_rn(f3));
            uint2 o;
            o.x = (unsigned)h0 | ((unsigned)h1 << 16);
            o.y = (unsigned)h2 | ((unsigned)h3 << 16);
            *reinterpret_cast<uint2*>(xTh32 + (size_t)(d0 + d) * 32 + jj * 2) = o;
        }
        return;
    }

    // ---- binpack: one-pass pack + ballot-bin (R23 verbatim) ----
    const int bid = blockIdx.x - TRANS_BLOCKS;   // 0..255
    const int w = t >> 6;
    const int dslice  = bid >> 2;
    const int quarter = bid & 3;
    const int sc      = quarter * 4 + w;
    const int d0      = dslice * SLICE + sc * SC_D;
    unsigned* regw = reg + ((size_t)(dslice * NSC + sc) * NBIN) * BCAP;
    const unsigned long long lmask = (1ull << lane) - 1ull;

    unsigned cb[16];
    #pragma unroll
    for (int b = 0; b < 16; ++b) cb[b] = 0;

    #pragma unroll
    for (int step = 0; step < SC_D / 64; ++step) {
        const int dli = step * 64 + lane;
        const int4 iv = reinterpret_cast<const int4*>(idx)[d0 + dli];
        const int4 sv = reinterpret_cast<const int4*>(sgn)[d0 + dli];
        const unsigned rowbyte = (unsigned)((sc * SC_D + dli) << 7);
        #pragma unroll
        for (int c = 0; c < 4; ++c) {
            const unsigned p = ((unsigned)((c==0)?iv.x:(c==1)?iv.y:(c==2)?iv.z:iv.w)) & 4095u;
            const unsigned s = ((unsigned)((c==0)?sv.x:(c==1)?sv.y:(c==2)?sv.z:sv.w)) & 1u;
            const unsigned e = rowbyte | ((p & 255u) << 19) | ((s ^ 1u) << 31);
            const unsigned bin = p >> 8;
            unsigned pos = 0;
            #pragma unroll
            for (int b = 0; b < 16; ++b) {
                const unsigned long long m = __ballot(bin == (unsigned)b);
                if (bin == (unsigned)b) pos = cb[b] + (unsigned)__popcll(m & lmask);
                cb[b] += (unsigned)__popcll(m);
            }
            if (pos < (unsigned)BCAP) regw[bin * BCAP + pos] = e;
        }
    }
    unsigned cval = 0;
    #pragma unroll
    for (int b = 0; b < 16; ++b) {
        const unsigned cc = cb[b] < (unsigned)BCAP ? cb[b] : (unsigned)BCAP;
        cval = (lane == b) ? cc : cval;
    }
    if (lane < 16) cnt[(dslice * NSC + sc) * NBIN + lane] = (int)cval;
}

// ---------------- K3: two-phase re-bin + scalar-guarded batch-8 process ----
__global__ __launch_bounds__(512, 8) void k_process(
    const unsigned* __restrict__ reg, const int* __restrict__ cnt,
    const unsigned short* __restrict__ xTh, __half* __restrict__ part) {
    __shared__ __half2 hist[WPB][2 * PR_W * 32];   // [w][side*512 + po*32 + word] 32 KB
    __shared__ unsigned lst[WPB][LCAP];            // contiguous per-target lists 4 KB
    __shared__ int cnts[WPB][WPB];                 // [scanwave][target]
    __shared__ int baseL[WPB][WPB];                // [target][scanwave]
    __shared__ int totals[WPB];

    const int w = threadIdx.x >> 6, lane = threadIdx.x & 63;
    const int dslice = blockIdx.x & 63;   // stride-64 peers share xTh slice/XCD
    const int hb  = blockIdx.x >> 6;      // 0..31
    const int bin = hb >> 1, half = hb & 1;

    __half2* hw = hist[w];
    {
        unsigned* h32 = reinterpret_cast<unsigned*>(hw);
        #pragma unroll
        for (int k = 0; k < 16; ++k) h32[k * 64 + lane] = 0u;
    }

    const unsigned long long lmask = (1ull << lane) - 1ull;

    // --- phase 1: count per (scanwave, target); stash entries in regs ---
    unsigned er[4];
    int n0 = 0, n1 = 0;
    int c0 = 0, c1 = 0, c2 = 0, c3 = 0, c4 = 0, c5 = 0, c6 = 0, c7 = 0;
    #pragma unroll
    for (int sc2 = 0; sc2 < 2; ++sc2) {
        const int sc = 2 * w + sc2;
        const int n  = cnt[(dslice * NSC + sc) * NBIN + bin];
        const unsigned* list = reg + ((size_t)((dslice * NSC + sc) * NBIN + bin)) * BCAP;
        if (sc2 == 0) n0 = n; else n1 = n;
        #pragma unroll
        for (int b = 0; b < 2; ++b) {
            const int i = b * 64 + lane;
            const unsigned e = (i < n) ? list[i] : 0u;
            er[sc2 * 2 + b] = e;
            const unsigned po8 = (e >> 19) & 255u;
            const bool valid = (i < n) && ((int)(po8 >> 7) == half);
            const unsigned t = valid ? ((po8 >> 4) & 7u) : 0xFFu;
            c0 += __popcll(__ballot(t == 0u)); c1 += __popcll(__ballot(t == 1u));
            c2 += __popcll(__ballot(t == 2u)); c3 += __popcll(__ballot(t == 3u));
            c4 += __popcll(__ballot(t == 4u)); c5 += __popcll(__ballot(t == 5u));
            c6 += __popcll(__ballot(t == 6u)); c7 += __popcll(__ballot(t == 7u));
        }
    }
    {
        int cval = 0;
        cval = (lane == 0) ? c0 : cval; cval = (lane == 1) ? c1 : cval;
        cval = (lane == 2) ? c2 : cval; cval = (lane == 3) ? c3 : cval;
        cval = (lane == 4) ? c4 : cval; cval = (lane == 5) ? c5 : cval;
        cval = (lane == 6) ? c6 : cval; cval = (lane == 7) ? c7 : cval;
        if (lane < 8) cnts[w][lane] = cval;
    }
    __syncthreads();

    if (w == 0 && lane < 8) {     // lane = target t
        int run = 0;
        #pragma unroll
        for (int ww = 0; ww < 8; ++ww) { baseL[lane][ww] = run; run += cnts[ww][lane]; }
        totals[lane] = run;
    }
    __syncthreads();

    // --- phase 2: re-ballot from regs, write contiguous target lists ---
    c0 = c1 = c2 = c3 = c4 = c5 = c6 = c7 = 0;
    #pragma unroll
    for (int sc2 = 0; sc2 < 2; ++sc2) {
        const int n = (sc2 == 0) ? n0 : n1;
        #pragma unroll
        for (int b = 0; b < 2; ++b) {
            const int i = b * 64 + lane;
            const unsigned e = er[sc2 * 2 + b];
            const unsigned po8 = (e >> 19) & 255u;
            const bool valid = (i < n) && ((int)(po8 >> 7) == half);
            const unsigned t = valid ? ((po8 >> 4) & 7u) : 0xFFu;
            const unsigned long long m0 = __ballot(t == 0u);
            const unsigned long long m1 = __ballot(t == 1u);
            const unsigned long long m2 = __ballot(t == 2u);
            const unsigned long long m3 = __ballot(t == 3u);
            const unsigned long long m4 = __ballot(t == 4u);
            const unsigned long long m5 = __ballot(t == 5u);
            const unsigned long long m6 = __ballot(t == 6u);
            const unsigned long long m7 = __ballot(t == 7u);
            if (valid) {
                const unsigned long long mt =
                    t < 4u ? (t < 2u ? (t == 0u ? m0 : m1) : (t == 2u ? m2 : m3))
                           : (t < 6u ? (t == 4u ? m4 : m5) : (t == 6u ? m6 : m7));
                const int cbase =
                    t < 4u ? (t < 2u ? (t == 0u ? c0 : c1) : (t == 2u ? c2 : c3))
                           : (t < 6u ? (t == 4u ? c4 : c5) : (t == 6u ? c6 : c7));
                const int pos = baseL[t][w] + cbase + (int)__popcll(mt & lmask);
                if (pos < LCAP) lst[t][pos] = e;
            }
            c0 += __popcll(m0); c1 += __popcll(m1);
            c2 += __popcll(m2); c3 += __popcll(m3);
            c4 += __popcll(m4); c5 += __popcll(m5);
            c6 += __popcll(m6); c7 += __popcll(m7);
        }
    }
    __syncthreads();

    // --- process: wave w consumes lst[w]; batches of 8, scalar dup-guard ---
    const char* xs_c = reinterpret_cast<const char*>(xTh) + (size_t)dslice * SLICE * 128;
    const unsigned li4 = (unsigned)(lane & 31) * 4u;
    const bool hi = lane >= 32;
    const unsigned l31 = (unsigned)(lane & 31);
    const int n = totals[w] < LCAP ? totals[w] : LCAP;
    const unsigned* L = lst[w];

    int i = 0;
    for (; i + 8 <= n; i += 8) {
        const uint4 A  = *reinterpret_cast<const uint4*>(L + i);
        const uint4 Bv = *reinterpret_cast<const uint4*>(L + i + 4);
        const unsigned e0 = __builtin_amdgcn_readfirstlane(A.x);
        const unsigned e1 = __builtin_amdgcn_readfirstlane(A.y);
        const unsigned e2 = __builtin_amdgcn_readfirstlane(A.z);
        const unsigned e3 = __builtin_amdgcn_readfirstlane(A.w);
        const unsigned e4 = __builtin_amdgcn_readfirstlane(Bv.x);
        const unsigned e5 = __builtin_amdgcn_readfirstlane(Bv.y);
        const unsigned e6 = __builtin_amdgcn_readfirstlane(Bv.z);
        const unsigned e7 = __builtin_amdgcn_readfirstlane(Bv.w);
        // entries 0-3 -> lo-half lanes, 4-7 -> hi-half lanes
        const unsigned va0 = (hi ? (e4 & 0x7FFFFu) : (e0 & 0x7FFFFu)) + li4;
        const unsigned va1 = (hi ? (e5 & 0x7FFFFu) : (e1 & 0x7FFFFu)) + li4;
        const unsigned va2 = (hi ? (e6 & 0x7FFFFu) : (e2 & 0x7FFFFu)) + li4;
        const unsigned va3 = (hi ? (e7 & 0x7FFFFu) : (e3 & 0x7FFFFu)) + li4;
        const unsigned d0 = *reinterpret_cast<const unsigned*>(xs_c + va0);
        const unsigned d1 = *reinterpret_cast<const unsigned*>(xs_c + va1);
        const unsigned d2 = *reinterpret_cast<const unsigned*>(xs_c + va2);
        const unsigned d3 = *reinterpret_cast<const unsigned*>(xs_c + va3);

        const unsigned pL0 = (e0 >> 19) & 15u, pL1 = (e1 >> 19) & 15u;
        const unsigned pL2 = (e2 >> 19) & 15u, pL3 = (e3 >> 19) & 15u;
        const unsigned pH0 = (e4 >> 19) & 15u, pH1 = (e5 >> 19) & 15u;
        const unsigned pH2 = (e6 >> 19) & 15u, pH3 = (e7 >> 19) & 15u;

        // f16 data: value = gathered dword XOR per-side sign mask (no cvt)
        __half2 v[4];
        #pragma unroll
        for (int k = 0; k < 4; ++k) {
            const unsigned dv = (k == 0) ? d0 : (k == 1) ? d1 : (k == 2) ? d2 : d3;
            const unsigned eL = (k == 0) ? e0 : (k == 1) ? e1 : (k == 2) ? e2 : e3;
            const unsigned eH = (k == 0) ? e4 : (k == 1) ? e5 : (k == 2) ? e6 : e7;
            const unsigned sm = hi ? (eH & 0x80000000u) : (eL & 0x80000000u);
            v[k] = __builtin_bit_cast(__half2, dv ^ (sm ? 0x80008000u : 0u));
        }

        const unsigned a0 = (hi ? (512u + pH0 * 32u) : (pL0 * 32u)) + l31;
        const unsigned a1 = (hi ? (512u + pH1 * 32u) : (pL1 * 32u)) + l31;
        const unsigned a2 = (hi ? (512u + pH2 * 32u) : (pL2 * 32u)) + l31;
        const unsigned a3 = (hi ? (512u + pH3 * 32u) : (pL3 * 32u)) + l31;

        // wave-uniform scalar dup check (po's are SGPRs via readfirstlane)
        const bool dupL = (pL0 == pL1) | (pL0 == pL2) | (pL0 == pL3)
                        | (pL1 == pL2) | (pL1 == pL3) | (pL2 == pL3);
        const bool dupH = (pH0 == pH1) | (pH0 == pH2) | (pH0 == pH3)
                        | (pH1 == pH2) | (pH1 == pH3) | (pH2 == pH3);
        if (!(dupL | dupH)) {
            // fast path: addresses distinct per side -> read-all / write-all
            const __half2 h0 = hw[a0];
            const __half2 h1 = hw[a1];
            const __half2 h2v = hw[a2];
            const __half2 h3 = hw[a3];
            hw[a0] = __hadd2(h0, v[0]);
            hw[a1] = __hadd2(h1, v[1]);
            hw[a2] = __hadd2(h2v, v[2]);
            hw[a3] = __hadd2(h3, v[3]);
        } else {
            // slow path (~17%): sequential RMWs, correct under any dups
            hw[a0] = __hadd2(hw[a0], v[0]);
            hw[a1] = __hadd2(hw[a1], v[1]);
            hw[a2] = __hadd2(hw[a2], v[2]);
            hw[a3] = __hadd2(hw[a3], v[3]);
        }
    }
    for (; i + 2 <= n; i += 2) {    // pair tail: lo/hi sides disjoint -> safe
        const unsigned eA = __builtin_amdgcn_readfirstlane(L[i]);
        const unsigned eB = __builtin_amdgcn_readfirstlane(L[i + 1]);
        const unsigned va = (hi ? (eB & 0x7FFFFu) : (eA & 0x7FFFFu)) + li4;
        const unsigned dv = *reinterpret_cast<const unsigned*>(xs_c + va);
        const unsigned sm = hi ? (eB & 0x80000000u) : (eA & 0x80000000u);
        const unsigned pkb = dv ^ (sm ? 0x80008000u : 0u);
        const unsigned po = hi ? ((eB >> 19) & 15u) : ((eA >> 19) & 15u);
        const unsigned a = (hi ? (512u + po * 32u) : (po * 32u)) + l31;
        hw[a] = __hadd2(hw[a], __builtin_bit_cast(__half2, pkb));
    }
    if (i < n) {                    // odd tail: lo half only
        const unsigned eA = __builtin_amdgcn_readfirstlane(L[i]);
        if (!hi) {
            const unsigned va = (eA & 0x7FFFFu) + li4;
            const unsigned dv = *reinterpret_cast<const unsigned*>(xs_c + va);
            const unsigned pkb = dv ^ ((eA & 0x80000000u) ? 0x80008000u : 0u);
            const unsigned a = ((eA >> 19) & 15u) * 32u + l31;
            hw[a] = __hadd2(hw[a], __builtin_bit_cast(__half2, pkb));
        }
    }

    // writeout: merge LO+HI, store to part (pr = hb*8 + w)
    unsigned* wp32 = reinterpret_cast<unsigned*>(
        part + ((size_t)((hb * WPB + w) * NDS + dslice)) * (PR_W * B_DIM));
    #pragma unroll
    for (int k = 0; k < 8; ++k) {
        const int idxw = k * 64 + lane;            // 0..511
        const __half2 s = __hadd2(hw[idxw], hw[512 + idxw]);
        wp32[idxw] = __builtin_bit_cast(unsigned, s);
    }
}

// ---------------- K4: reduce partials -> out (NPR=256) ----------------
__global__ __launch_bounds__(256) void k_reduce(
    const __half* __restrict__ part, float* __restrict__ out) {
    const int pr = blockIdx.x;       // p-range 0..255 (16 wide)
    const int t  = threadIdx.x;

    float4 acc = make_float4(0.f, 0.f, 0.f, 0.f);
    const size_t base = (size_t)pr * NDS * (PR_W * B_DIM);
    for (int ds = 0; ds < NDS; ++ds) {
        const uint2 pv = *reinterpret_cast<const uint2*>(
            part + base + (size_t)ds * (PR_W * B_DIM) + t * 4);
        const __half2 h0 = __builtin_bit_cast(__half2, pv.x);
        const __half2 h1 = __builtin_bit_cast(__half2, pv.y);
        acc.x += __half2float(h0.x); acc.y += __half2float(h0.y);
        acc.z += __half2float(h1.x); acc.w += __half2float(h1.y);
    }

    __shared__ float st[16][65];
    const int po = (t * 4) >> 6;          // 0..15
    const int b0 = (t * 4) & 63;
    st[po][b0]     = acc.x; st[po][b0 + 1] = acc.y;
    st[po][b0 + 2] = acc.z; st[po][b0 + 3] = acc.w;
    __syncthreads();

    #pragma unroll
    for (int k = 0; k < 4; ++k) {
        const int flat = k * 256 + t;     // b*16 + po
        const int b = flat >> 4, poo = flat & 15;
        out[(size_t)b * P_DIM + pr * PR_W + poo] = st[poo][b];
    }
}

// ---------------- fallback: LDS-atomic histogram ----------------
__device__ __forceinline__ float signed_val(float x, int s) {
    return __uint_as_float(__float_as_uint(x) ^ (((unsigned)(s ^ 1)) << 31));
}

__global__ __launch_bounds__(1024) void sjlt_hist_fb(
    const float* __restrict__ x, const int* __restrict__ idx,
    const int* __restrict__ sgn, float* __restrict__ out) {
    __shared__ float hist[2][P_DIM];
    for (int i = threadIdx.x; i < 2 * P_DIM; i += 1024) (&hist[0][0])[i] = 0.0f;
    __syncthreads();
    const int chunk = blockIdx.x, bg = blockIdx.y;
    const int d0 = chunk * (D_DIM / 16), b0 = bg * 2;
    const float* xr0 = x + (size_t)b0 * D_DIM + d0;
    const float* xr1 = xr0 + D_DIM;
    const int4* iv4 = reinterpret_cast<const int4*>(idx) + d0;
    const int4* sv4 = reinterpret_cast<const int4*>(sgn) + d0;
    for (int t = threadIdx.x; t < D_DIM / 16; t += 1024) {
        const int4 iv = iv4[t]; const int4 sv = sv4[t];
        const float x0 = xr0[t], x1 = xr1[t];
        unsafeAtomicAdd(&hist[0][iv.x], signed_val(x0, sv.x));
        unsafeAtomicAdd(&hist[0][iv.y], signed_val(x0, sv.y));
        unsafeAtomicAdd(&hist[0][iv.z], signed_val(x0, sv.z));
        unsafeAtomicAdd(&hist[0][iv.w], signed_val(x0, sv.w));
        unsafeAtomicAdd(&hist[1][iv.x], signed_val(x1, sv.x));
        unsafeAtomicAdd(&hist[1][iv.y], signed_val(x1, sv.y));
        unsafeAtomicAdd(&hist[1][iv.z], signed_val(x1, sv.z));
        unsafeAtomicAdd(&hist[1][iv.w], signed_val(x1, sv.w));
    }
    __syncthreads();
    float* o = out + (size_t)b0 * P_DIM;
    for (int p = threadIdx.x; p < P_DIM; p += 1024) {
        unsafeAtomicAdd(&o[p],         hist[0][p]);
        unsafeAtomicAdd(&o[P_DIM + p], hist[1][p]);
    }
}

extern "C" void kernel_launch(void* const* d_in, const int* in_sizes, int n_in,
                              void* d_out, int out_size, void* d_ws, size_t ws_size,
                              hipStream_t stream) {
    const float* x   = (const float*)d_in[0];
    const int*   idx = (const int*)d_in[1];
    const int*   sgn = (const int*)d_in[2];
    float* out = (float*)d_out;

    if (ws_size >= WS_NEED) {
        char* ws = (char*)d_ws;
        unsigned* reg = (unsigned*)(ws + REG_OFF);
        int* cnt      = (int*)(ws + CNT_OFF);
        unsigned short* xTh = (unsigned short*)(ws + XT_OFF);
        __half* part  = (__half*)(ws + PART_OFF);

        k_prep<<<TRANS_BLOCKS + BINPK_BLOCKS, 256, 0, stream>>>(x, idx, sgn, xTh, reg, cnt);
        k_process<<<NHB * NDS, 512, 0, stream>>>(reg, cnt, xTh, part);
        k_reduce<<<NPR, 256, 0, stream>>>(part, out);
    } else {
        hipMemsetAsync(d_out, 0, (size_t)out_size * sizeof(float), stream);
        dim3 grid(16, 32);
        sjlt_hist_fb<<<grid, 1024, 0, stream>>>(x, idx, sgn, out);
    }
}

// Round 25
// 69.972 us; speedup vs baseline: 1.0449x; 1.0449x over previous
//
#include <hip/hip_runtime.h>
#include <hip/hip_bf16.h>
#include <hip/hip_fp16.h>

// SJLT projection: out[b, idx[d,c]] += x[b,d] * (2*sign[d,c]-1)
// B=64, D=262144, C=4, P=4096
//
// R25 = R23 with the transpose vectorized USING CONFLICT-CLEAN primitives.
// R24 post-mortem: 4-consecutive-float LDS reads per lane got merged into
// wide LDS ops -> ~8-way bank conflicts (1.05M counted), prep 38.7->44.6us.
// Fix: every LDS instruction is ONE 4B element per lane in the class R23
// measured at zero conflicts (<=2 lanes/bank):
//   phase 1: float2 global loads (8B/lane) + 2 scalar LDS writes
//            (bank = (2c2+k+b)%32, 2-way).
//   phase 2: lane = (d-pair, b-pair): 2 scalar LDS reads
//            (bank = (d+2*bcol)%32, 2-way), cvt+pack, uint store (4B/lane).
// Per-thread instrs 64->48, wider global transactions.
// binpack branch, k_process, k_reduce: R23 verbatim.

constexpr int B_DIM = 64;
constexpr int D_DIM = 262144;
constexpr int P_DIM = 4096;

constexpr int NDS   = 64;
constexpr int SLICE = D_DIM / NDS;      // 4096
constexpr int NBIN  = 16;               // binpack bins (256-wide)
constexpr int NSC   = 16;               // scanners per dslice
constexpr int SC_D  = SLICE / NSC;      // 256
constexpr int BCAP  = 128;              // per (dslice,sc,bin): mean 64, 8 sigma
constexpr int NHB   = 32;               // half-bins (128-wide)
constexpr int WPB   = 8;
constexpr int PR_W  = 16;               // p-slots per wave
constexpr int NPR   = P_DIM / PR_W;     // 256
constexpr int LCAP  = 128;              // per-wave list: mean 64, 8 sigma

constexpr int TRANS_BLOCKS = D_DIM / 64;   // 4096
constexpr int BINPK_BLOCKS = NDS * 4;      // 256

// ---- ws layout ----
constexpr size_t REG_OFF   = 0;
constexpr size_t REG_BYTES = (size_t)NDS * NSC * NBIN * BCAP * 4;          // 8.4 MB
constexpr size_t CNT_OFF   = REG_OFF + REG_BYTES;
constexpr size_t CNT_BYTES = (size_t)NDS * NSC * NBIN * 4;                 // 64 KB
constexpr size_t XT_OFF    = CNT_OFF + CNT_BYTES;
constexpr size_t XT_BYTES  = (size_t)D_DIM * B_DIM * 2;                    // 33.5 MB
constexpr size_t PART_OFF  = XT_OFF + XT_BYTES;
constexpr size_t PART_BYTES = (size_t)NPR * NDS * PR_W * B_DIM * 2;        // 33.5 MB
constexpr size_t WS_NEED   = PART_OFF + PART_BYTES;                        // ~76 MB

// ---------------- K1: merged transpose (f16, conflict-clean) + binpack ------
// binpack entry u32: bits 0-18 rowbyte (dloc-in-slice*128), 19-26 p&255,
//                    bit 31 = (sv^1) -> negate when set.
__global__ __launch_bounds__(256) void k_prep(
    const float* __restrict__ x,
    const int* __restrict__ idx, const int* __restrict__ sgn,
    unsigned short* __restrict__ xTh,
    unsigned* __restrict__ reg, int* __restrict__ cnt) {
    __shared__ float tile[64 * 65];
    const int t = threadIdx.x;
    const int lane = t & 63;

    if (blockIdx.x < TRANS_BLOCKS) {
        const int d0 = blockIdx.x * 64;
        // phase 1: float2 reads (8B/lane); 2 scalar LDS writes, 2-way banks
        #pragma unroll
        for (int i = 0; i < 8; ++i) {
            const int flat = i * 256 + t;          // 0..2047
            const int b  = flat >> 5;              // 0..63
            const int c2 = flat & 31;              // float2 col
            const float2 v = *reinterpret_cast<const float2*>(
                x + (size_t)b * D_DIM + d0 + c2 * 2);
            tile[(c2 * 2 + 0) * 65 + b] = v.x;
            tile[(c2 * 2 + 1) * 65 + b] = v.y;
        }
        __syncthreads();
        // phase 2: 2 scalar LDS reads (2-way banks), pack, uint store
        unsigned* xTh32 = reinterpret_cast<unsigned*>(xTh);
        #pragma unroll
        for (int i = 0; i < 8; ++i) {
            const int flat = i * 256 + t;          // 0..2047
            const int d    = flat >> 5;            // 0..63
            const int bcol = flat & 31;            // b-pair col
            const float f0 = tile[d * 65 + bcol * 2 + 0];
            const float f1 = tile[d * 65 + bcol * 2 + 1];
            const unsigned short h0 = __builtin_bit_cast(unsigned short, __float2half_rn(f0));
            const unsigned short h1 = __builtin_bit_cast(unsigned short, __float2half_rn(f1));
            xTh32[(size_t)(d0 + d) * 32 + bcol] = (unsigned)h0 | ((unsigned)h1 << 16);
        }
        return;
    }

    // ---- binpack: one-pass pack + ballot-bin (R23 verbatim) ----
    const int bid = blockIdx.x - TRANS_BLOCKS;   // 0..255
    const int w = t >> 6;
    const int dslice  = bid >> 2;
    const int quarter = bid & 3;
    const int sc      = quarter * 4 + w;
    const int d0      = dslice * SLICE + sc * SC_D;
    unsigned* regw = reg + ((size_t)(dslice * NSC + sc) * NBIN) * BCAP;
    const unsigned long long lmask = (1ull << lane) - 1ull;

    unsigned cb[16];
    #pragma unroll
    for (int b = 0; b < 16; ++b) cb[b] = 0;

    #pragma unroll
    for (int step = 0; step < SC_D / 64; ++step) {
        const int dli = step * 64 + lane;
        const int4 iv = reinterpret_cast<const int4*>(idx)[d0 + dli];
        const int4 sv = reinterpret_cast<const int4*>(sgn)[d0 + dli];
        const unsigned rowbyte = (unsigned)((sc * SC_D + dli) << 7);
        #pragma unroll
        for (int c = 0; c < 4; ++c) {
            const unsigned p = ((unsigned)((c==0)?iv.x:(c==1)?iv.y:(c==2)?iv.z:iv.w)) & 4095u;
            const unsigned s = ((unsigned)((c==0)?sv.x:(c==1)?sv.y:(c==2)?sv.z:sv.w)) & 1u;
            const unsigned e = rowbyte | ((p & 255u) << 19) | ((s ^ 1u) << 31);
            const unsigned bin = p >> 8;
            unsigned pos = 0;
            #pragma unroll
            for (int b = 0; b < 16; ++b) {
                const unsigned long long m = __ballot(bin == (unsigned)b);
                if (bin == (unsigned)b) pos = cb[b] + (unsigned)__popcll(m & lmask);
                cb[b] += (unsigned)__popcll(m);
            }
            if (pos < (unsigned)BCAP) regw[bin * BCAP + pos] = e;
        }
    }
    unsigned cval = 0;
    #pragma unroll
    for (int b = 0; b < 16; ++b) {
        const unsigned cc = cb[b] < (unsigned)BCAP ? cb[b] : (unsigned)BCAP;
        cval = (lane == b) ? cc : cval;
    }
    if (lane < 16) cnt[(dslice * NSC + sc) * NBIN + lane] = (int)cval;
}

// ---------------- K3: two-phase re-bin + scalar-guarded batch-8 process ----
__global__ __launch_bounds__(512, 8) void k_process(
    const unsigned* __restrict__ reg, const int* __restrict__ cnt,
    const unsigned short* __restrict__ xTh, __half* __restrict__ part) {
    __shared__ __half2 hist[WPB][2 * PR_W * 32];   // [w][side*512 + po*32 + word] 32 KB
    __shared__ unsigned lst[WPB][LCAP];            // contiguous per-target lists 4 KB
    __shared__ int cnts[WPB][WPB];                 // [scanwave][target]
    __shared__ int baseL[WPB][WPB];                // [target][scanwave]
    __shared__ int totals[WPB];

    const int w = threadIdx.x >> 6, lane = threadIdx.x & 63;
    const int dslice = blockIdx.x & 63;   // stride-64 peers share xTh slice/XCD
    const int hb  = blockIdx.x >> 6;      // 0..31
    const int bin = hb >> 1, half = hb & 1;

    __half2* hw = hist[w];
    {
        unsigned* h32 = reinterpret_cast<unsigned*>(hw);
        #pragma unroll
        for (int k = 0; k < 16; ++k) h32[k * 64 + lane] = 0u;
    }

    const unsigned long long lmask = (1ull << lane) - 1ull;

    // --- phase 1: count per (scanwave, target); stash entries in regs ---
    unsigned er[4];
    int n0 = 0, n1 = 0;
    int c0 = 0, c1 = 0, c2 = 0, c3 = 0, c4 = 0, c5 = 0, c6 = 0, c7 = 0;
    #pragma unroll
    for (int sc2 = 0; sc2 < 2; ++sc2) {
        const int sc = 2 * w + sc2;
        const int n  = cnt[(dslice * NSC + sc) * NBIN + bin];
        const unsigned* list = reg + ((size_t)((dslice * NSC + sc) * NBIN + bin)) * BCAP;
        if (sc2 == 0) n0 = n; else n1 = n;
        #pragma unroll
        for (int b = 0; b < 2; ++b) {
            const int i = b * 64 + lane;
            const unsigned e = (i < n) ? list[i] : 0u;
            er[sc2 * 2 + b] = e;
            const unsigned po8 = (e >> 19) & 255u;
            const bool valid = (i < n) && ((int)(po8 >> 7) == half);
            const unsigned t = valid ? ((po8 >> 4) & 7u) : 0xFFu;
            c0 += __popcll(__ballot(t == 0u)); c1 += __popcll(__ballot(t == 1u));
            c2 += __popcll(__ballot(t == 2u)); c3 += __popcll(__ballot(t == 3u));
            c4 += __popcll(__ballot(t == 4u)); c5 += __popcll(__ballot(t == 5u));
            c6 += __popcll(__ballot(t == 6u)); c7 += __popcll(__ballot(t == 7u));
        }
    }
    {
        int cval = 0;
        cval = (lane == 0) ? c0 : cval; cval = (lane == 1) ? c1 : cval;
        cval = (lane == 2) ? c2 : cval; cval = (lane == 3) ? c3 : cval;
        cval = (lane == 4) ? c4 : cval; cval = (lane == 5) ? c5 : cval;
        cval = (lane == 6) ? c6 : cval; cval = (lane == 7) ? c7 : cval;
        if (lane < 8) cnts[w][lane] = cval;
    }
    __syncthreads();

    if (w == 0 && lane < 8) {     // lane = target t
        int run = 0;
        #pragma unroll
        for (int ww = 0; ww < 8; ++ww) { baseL[lane][ww] = run; run += cnts[ww][lane]; }
        totals[lane] = run;
    }
    __syncthreads();

    // --- phase 2: re-ballot from regs, write contiguous target lists ---
    c0 = c1 = c2 = c3 = c4 = c5 = c6 = c7 = 0;
    #pragma unroll
    for (int sc2 = 0; sc2 < 2; ++sc2) {
        const int n = (sc2 == 0) ? n0 : n1;
        #pragma unroll
        for (int b = 0; b < 2; ++b) {
            const int i = b * 64 + lane;
            const unsigned e = er[sc2 * 2 + b];
            const unsigned po8 = (e >> 19) & 255u;
            const bool valid = (i < n) && ((int)(po8 >> 7) == half);
            const unsigned t = valid ? ((po8 >> 4) & 7u) : 0xFFu;
            const unsigned long long m0 = __ballot(t == 0u);
            const unsigned long long m1 = __ballot(t == 1u);
            const unsigned long long m2 = __ballot(t == 2u);
            const unsigned long long m3 = __ballot(t == 3u);
            const unsigned long long m4 = __ballot(t == 4u);
            const unsigned long long m5 = __ballot(t == 5u);
            const unsigned long long m6 = __ballot(t == 6u);
            const unsigned long long m7 = __ballot(t == 7u);
            if (valid) {
                const unsigned long long mt =
                    t < 4u ? (t < 2u ? (t == 0u ? m0 : m1) : (t == 2u ? m2 : m3))
                           : (t < 6u ? (t == 4u ? m4 : m5) : (t == 6u ? m6 : m7));
                const int cbase =
                    t < 4u ? (t < 2u ? (t == 0u ? c0 : c1) : (t == 2u ? c2 : c3))
                           : (t < 6u ? (t == 4u ? c4 : c5) : (t == 6u ? c6 : c7));
                const int pos = baseL[t][w] + cbase + (int)__popcll(mt & lmask);
                if (pos < LCAP) lst[t][pos] = e;
            }
            c0 += __popcll(m0); c1 += __popcll(m1);
            c2 += __popcll(m2); c3 += __popcll(m3);
            c4 += __popcll(m4); c5 += __popcll(m5);
            c6 += __popcll(m6); c7 += __popcll(m7);
        }
    }
    __syncthreads();

    // --- process: wave w consumes lst[w]; batches of 8, scalar dup-guard ---
    const char* xs_c = reinterpret_cast<const char*>(xTh) + (size_t)dslice * SLICE * 128;
    const unsigned li4 = (unsigned)(lane & 31) * 4u;
    const bool hi = lane >= 32;
    const unsigned l31 = (unsigned)(lane & 31);
    const int n = totals[w] < LCAP ? totals[w] : LCAP;
    const unsigned* L = lst[w];

    int i = 0;
    for (; i + 8 <= n; i += 8) {
        const uint4 A  = *reinterpret_cast<const uint4*>(L + i);
        const uint4 Bv = *reinterpret_cast<const uint4*>(L + i + 4);
        const unsigned e0 = __builtin_amdgcn_readfirstlane(A.x);
        const unsigned e1 = __builtin_amdgcn_readfirstlane(A.y);
        const unsigned e2 = __builtin_amdgcn_readfirstlane(A.z);
        const unsigned e3 = __builtin_amdgcn_readfirstlane(A.w);
        const unsigned e4 = __builtin_amdgcn_readfirstlane(Bv.x);
        const unsigned e5 = __builtin_amdgcn_readfirstlane(Bv.y);
        const unsigned e6 = __builtin_amdgcn_readfirstlane(Bv.z);
        const unsigned e7 = __builtin_amdgcn_readfirstlane(Bv.w);
        // entries 0-3 -> lo-half lanes, 4-7 -> hi-half lanes
        const unsigned va0 = (hi ? (e4 & 0x7FFFFu) : (e0 & 0x7FFFFu)) + li4;
        const unsigned va1 = (hi ? (e5 & 0x7FFFFu) : (e1 & 0x7FFFFu)) + li4;
        const unsigned va2 = (hi ? (e6 & 0x7FFFFu) : (e2 & 0x7FFFFu)) + li4;
        const unsigned va3 = (hi ? (e7 & 0x7FFFFu) : (e3 & 0x7FFFFu)) + li4;
        const unsigned d0 = *reinterpret_cast<const unsigned*>(xs_c + va0);
        const unsigned d1 = *reinterpret_cast<const unsigned*>(xs_c + va1);
        const unsigned d2 = *reinterpret_cast<const unsigned*>(xs_c + va2);
        const unsigned d3 = *reinterpret_cast<const unsigned*>(xs_c + va3);

        const unsigned pL0 = (e0 >> 19) & 15u, pL1 = (e1 >> 19) & 15u;
        const unsigned pL2 = (e2 >> 19) & 15u, pL3 = (e3 >> 19) & 15u;
        const unsigned pH0 = (e4 >> 19) & 15u, pH1 = (e5 >> 19) & 15u;
        const unsigned pH2 = (e6 >> 19) & 15u, pH3 = (e7 >> 19) & 15u;

        // f16 data: value = gathered dword XOR per-side sign mask (no cvt)
        __half2 v[4];
        #pragma unroll
        for (int k = 0; k < 4; ++k) {
            const unsigned dv = (k == 0) ? d0 : (k == 1) ? d1 : (k == 2) ? d2 : d3;
            const unsigned eL = (k == 0) ? e0 : (k == 1) ? e1 : (k == 2) ? e2 : e3;
            const unsigned eH = (k == 0) ? e4 : (k == 1) ? e5 : (k == 2) ? e6 : e7;
            const unsigned sm = hi ? (eH & 0x80000000u) : (eL & 0x80000000u);
            v[k] = __builtin_bit_cast(__half2, dv ^ (sm ? 0x80008000u : 0u));
        }

        const unsigned a0 = (hi ? (512u + pH0 * 32u) : (pL0 * 32u)) + l31;
        const unsigned a1 = (hi ? (512u + pH1 * 32u) : (pL1 * 32u)) + l31;
        const unsigned a2 = (hi ? (512u + pH2 * 32u) : (pL2 * 32u)) + l31;
        const unsigned a3 = (hi ? (512u + pH3 * 32u) : (pL3 * 32u)) + l31;

        // wave-uniform scalar dup check (po's are SGPRs via readfirstlane)
        const bool dupL = (pL0 == pL1) | (pL0 == pL2) | (pL0 == pL3)
                        | (pL1 == pL2) | (pL1 == pL3) | (pL2 == pL3);
        const bool dupH = (pH0 == pH1) | (pH0 == pH2) | (pH0 == pH3)
                        | (pH1 == pH2) | (pH1 == pH3) | (pH2 == pH3);
        if (!(dupL | dupH)) {
            // fast path: addresses distinct per side -> read-all / write-all
            const __half2 h0 = hw[a0];
            const __half2 h1 = hw[a1];
            const __half2 h2v = hw[a2];
            const __half2 h3 = hw[a3];
            hw[a0] = __hadd2(h0, v[0]);
            hw[a1] = __hadd2(h1, v[1]);
            hw[a2] = __hadd2(h2v, v[2]);
            hw[a3] = __hadd2(h3, v[3]);
        } else {
            // slow path (~17%): sequential RMWs, correct under any dups
            hw[a0] = __hadd2(hw[a0], v[0]);
            hw[a1] = __hadd2(hw[a1], v[1]);
            hw[a2] = __hadd2(hw[a2], v[2]);
            hw[a3] = __hadd2(hw[a3], v[3]);
        }
    }
    for (; i + 2 <= n; i += 2) {    // pair tail: lo/hi sides disjoint -> safe
        const unsigned eA = __builtin_amdgcn_readfirstlane(L[i]);
        const unsigned eB = __builtin_amdgcn_readfirstlane(L[i + 1]);
        const unsigned va = (hi ? (eB & 0x7FFFFu) : (eA & 0x7FFFFu)) + li4;
        const unsigned dv = *reinterpret_cast<const unsigned*>(xs_c + va);
        const unsigned sm = hi ? (eB & 0x80000000u) : (eA & 0x80000000u);
        const unsigned pkb = dv ^ (sm ? 0x80008000u : 0u);
        const unsigned po = hi ? ((eB >> 19) & 15u) : ((eA >> 19) & 15u);
        const unsigned a = (hi ? (512u + po * 32u) : (po * 32u)) + l31;
        hw[a] = __hadd2(hw[a], __builtin_bit_cast(__half2, pkb));
    }
    if (i < n) {                    // odd tail: lo half only
        const unsigned eA = __builtin_amdgcn_readfirstlane(L[i]);
        if (!hi) {
            const unsigned va = (eA & 0x7FFFFu) + li4;
            const unsigned dv = *reinterpret_cast<const unsigned*>(xs_c + va);
            const unsigned pkb = dv ^ ((eA & 0x80000000u) ? 0x80008000u : 0u);
            const unsigned a = ((eA >> 19) & 15u) * 32u + l31;
            hw[a] = __hadd2(hw[a], __builtin_bit_cast(__half2, pkb));
        }
    }

    // writeout: merge LO+HI, store to part (pr = hb*8 + w)
    unsigned* wp32 = reinterpret_cast<unsigned*>(
        part + ((size_t)((hb * WPB + w) * NDS + dslice)) * (PR_W * B_DIM));
    #pragma unroll
    for (int k = 0; k < 8; ++k) {
        const int idxw = k * 64 + lane;            // 0..511
        const __half2 s = __hadd2(hw[idxw], hw[512 + idxw]);
        wp32[idxw] = __builtin_bit_cast(unsigned, s);
    }
}

// ---------------- K4: reduce partials -> out (NPR=256) ----------------
__global__ __launch_bounds__(256) void k_reduce(
    const __half* __restrict__ part, float* __restrict__ out) {
    const int pr = blockIdx.x;       // p-range 0..255 (16 wide)
    const int t  = threadIdx.x;

    float4 acc = make_float4(0.f, 0.f, 0.f, 0.f);
    const size_t base = (size_t)pr * NDS * (PR_W * B_DIM);
    for (int ds = 0; ds < NDS; ++ds) {
        const uint2 pv = *reinterpret_cast<const uint2*>(
            part + base + (size_t)ds * (PR_W * B_DIM) + t * 4);
        const __half2 h0 = __builtin_bit_cast(__half2, pv.x);
        const __half2 h1 = __builtin_bit_cast(__half2, pv.y);
        acc.x += __half2float(h0.x); acc.y += __half2float(h0.y);
        acc.z += __half2float(h1.x); acc.w += __half2float(h1.y);
    }

    __shared__ float st[16][65];
    const int po = (t * 4) >> 6;          // 0..15
    const int b0 = (t * 4) & 63;
    st[po][b0]     = acc.x; st[po][b0 + 1] = acc.y;
    st[po][b0 + 2] = acc.z; st[po][b0 + 3] = acc.w;
    __syncthreads();

    #pragma unroll
    for (int k = 0; k < 4; ++k) {
        const int flat = k * 256 + t;     // b*16 + po
        const int b = flat >> 4, poo = flat & 15;
        out[(size_t)b * P_DIM + pr * PR_W + poo] = st[poo][b];
    }
}

// ---------------- fallback: LDS-atomic histogram ----------------
__device__ __forceinline__ float signed_val(float x, int s) {
    return __uint_as_float(__float_as_uint(x) ^ (((unsigned)(s ^ 1)) << 31));
}

__global__ __launch_bounds__(1024) void sjlt_hist_fb(
    const float* __restrict__ x, const int* __restrict__ idx,
    const int* __restrict__ sgn, float* __restrict__ out) {
    __shared__ float hist[2][P_DIM];
    for (int i = threadIdx.x; i < 2 * P_DIM; i += 1024) (&hist[0][0])[i] = 0.0f;
    __syncthreads();
    const int chunk = blockIdx.x, bg = blockIdx.y;
    const int d0 = chunk * (D_DIM / 16), b0 = bg * 2;
    const float* xr0 = x + (size_t)b0 * D_DIM + d0;
    const float* xr1 = xr0 + D_DIM;
    const int4* iv4 = reinterpret_cast<const int4*>(idx) + d0;
    const int4* sv4 = reinterpret_cast<const int4*>(sgn) + d0;
    for (int t = threadIdx.x; t < D_DIM / 16; t += 1024) {
        const int4 iv = iv4[t]; const int4 sv = sv4[t];
        const float x0 = xr0[t], x1 = xr1[t];
        unsafeAtomicAdd(&hist[0][iv.x], signed_val(x0, sv.x));
        unsafeAtomicAdd(&hist[0][iv.y], signed_val(x0, sv.y));
        unsafeAtomicAdd(&hist[0][iv.z], signed_val(x0, sv.z));
        unsafeAtomicAdd(&hist[0][iv.w], signed_val(x0, sv.w));
        unsafeAtomicAdd(&hist[1][iv.x], signed_val(x1, sv.x));
        unsafeAtomicAdd(&hist[1][iv.y], signed_val(x1, sv.y));
        unsafeAtomicAdd(&hist[1][iv.z], signed_val(x1, sv.z));
        unsafeAtomicAdd(&hist[1][iv.w], signed_val(x1, sv.w));
    }
    __syncthreads();
    float* o = out + (size_t)b0 * P_DIM;
    for (int p = threadIdx.x; p < P_DIM; p += 1024) {
        unsafeAtomicAdd(&o[p],         hist[0][p]);
        unsafeAtomicAdd(&o[P_DIM + p], hist[1][p]);
    }
}

extern "C" void kernel_launch(void* const* d_in, const int* in_sizes, int n_in,
                              void* d_out, int out_size, void* d_ws, size_t ws_size,
                              hipStream_t stream) {
    const float* x   = (const float*)d_in[0];
    const int*   idx = (const int*)d_in[1];
    const int*   sgn = (const int*)d_in[2];
    float* out = (float*)d_out;

    if (ws_size >= WS_NEED) {
        char* ws = (char*)d_ws;
        unsigned* reg = (unsigned*)(ws + REG_OFF);
        int* cnt      = (int*)(ws + CNT_OFF);
        unsigned short* xTh = (unsigned short*)(ws + XT_OFF);
        __half* part  = (__half*)(ws + PART_OFF);

        k_prep<<<TRANS_BLOCKS + BINPK_BLOCKS, 256, 0, stream>>>(x, idx, sgn, xTh, reg, cnt);
        k_process<<<NHB * NDS, 512, 0, stream>>>(reg, cnt, xTh, part);
        k_reduce<<<NPR, 256, 0, stream>>>(part, out);
    } else {
        hipMemsetAsync(d_out, 0, (size_t)out_size * sizeof(float), stream);
        dim3 grid(16, 32);
        sjlt_hist_fb<<<grid, 1024, 0, stream>>>(x, idx, sgn, out);
    }
}

// Round 26
// 63.545 us; speedup vs baseline: 1.1506x; 1.1011x over previous
//
#include <hip/hip_runtime.h>
#include <hip/hip_bf16.h>
#include <hip/hip_fp16.h>

// SJLT projection: out[b, idx[d,c]] += x[b,d] * (2*sign[d,c]-1)
// B=64, D=262144, C=4, P=4096
//
// R26 = R25 with binpack blocks FIRST in the k_prep grid (single change).
// R25 post-mortem: prep's conflicts fixed but total unchanged at ~70us ->
// the residual is a SCHEDULING tail: the 256 binpack blocks were last in
// the 4352-block grid, running alone at 1 block/CU (1 wave/SIMD) for
// ~12us after the transposes drained. Putting them first overlaps that
// work with the 4096 transpose blocks. Zero logic change (disjoint data).
// k_process (batch-8 scalar-guarded), k_reduce: R23/R25 verbatim.

constexpr int B_DIM = 64;
constexpr int D_DIM = 262144;
constexpr int P_DIM = 4096;

constexpr int NDS   = 64;
constexpr int SLICE = D_DIM / NDS;      // 4096
constexpr int NBIN  = 16;               // binpack bins (256-wide)
constexpr int NSC   = 16;               // scanners per dslice
constexpr int SC_D  = SLICE / NSC;      // 256
constexpr int BCAP  = 128;              // per (dslice,sc,bin): mean 64, 8 sigma
constexpr int NHB   = 32;               // half-bins (128-wide)
constexpr int WPB   = 8;
constexpr int PR_W  = 16;               // p-slots per wave
constexpr int NPR   = P_DIM / PR_W;     // 256
constexpr int LCAP  = 128;              // per-wave list: mean 64, 8 sigma

constexpr int TRANS_BLOCKS = D_DIM / 64;   // 4096
constexpr int BINPK_BLOCKS = NDS * 4;      // 256

// ---- ws layout ----
constexpr size_t REG_OFF   = 0;
constexpr size_t REG_BYTES = (size_t)NDS * NSC * NBIN * BCAP * 4;          // 8.4 MB
constexpr size_t CNT_OFF   = REG_OFF + REG_BYTES;
constexpr size_t CNT_BYTES = (size_t)NDS * NSC * NBIN * 4;                 // 64 KB
constexpr size_t XT_OFF    = CNT_OFF + CNT_BYTES;
constexpr size_t XT_BYTES  = (size_t)D_DIM * B_DIM * 2;                    // 33.5 MB
constexpr size_t PART_OFF  = XT_OFF + XT_BYTES;
constexpr size_t PART_BYTES = (size_t)NPR * NDS * PR_W * B_DIM * 2;        // 33.5 MB
constexpr size_t WS_NEED   = PART_OFF + PART_BYTES;                        // ~76 MB

// ---------------- K1: merged binpack (FIRST) + transpose (f16) --------------
// binpack entry u32: bits 0-18 rowbyte (dloc-in-slice*128), 19-26 p&255,
//                    bit 31 = (sv^1) -> negate when set.
__global__ __launch_bounds__(256) void k_prep(
    const float* __restrict__ x,
    const int* __restrict__ idx, const int* __restrict__ sgn,
    unsigned short* __restrict__ xTh,
    unsigned* __restrict__ reg, int* __restrict__ cnt) {
    __shared__ float tile[64 * 65];
    const int t = threadIdx.x;
    const int lane = t & 63;

    if (blockIdx.x >= BINPK_BLOCKS) {
        // ---- transpose x[64][D] -> xTh[D][64] (f16), conflict-clean ----
        const int d0 = (blockIdx.x - BINPK_BLOCKS) * 64;
        // phase 1: float2 reads (8B/lane); 2 scalar LDS writes, 2-way banks
        #pragma unroll
        for (int i = 0; i < 8; ++i) {
            const int flat = i * 256 + t;          // 0..2047
            const int b  = flat >> 5;              // 0..63
            const int c2 = flat & 31;              // float2 col
            const float2 v = *reinterpret_cast<const float2*>(
                x + (size_t)b * D_DIM + d0 + c2 * 2);
            tile[(c2 * 2 + 0) * 65 + b] = v.x;
            tile[(c2 * 2 + 1) * 65 + b] = v.y;
        }
        __syncthreads();
        // phase 2: 2 scalar LDS reads (2-way banks), pack, uint store
        unsigned* xTh32 = reinterpret_cast<unsigned*>(xTh);
        #pragma unroll
        for (int i = 0; i < 8; ++i) {
            const int flat = i * 256 + t;          // 0..2047
            const int d    = flat >> 5;            // 0..63
            const int bcol = flat & 31;            // b-pair col
            const float f0 = tile[d * 65 + bcol * 2 + 0];
            const float f1 = tile[d * 65 + bcol * 2 + 1];
            const unsigned short h0 = __builtin_bit_cast(unsigned short, __float2half_rn(f0));
            const unsigned short h1 = __builtin_bit_cast(unsigned short, __float2half_rn(f1));
            xTh32[(size_t)(d0 + d) * 32 + bcol] = (unsigned)h0 | ((unsigned)h1 << 16);
        }
        return;
    }

    // ---- binpack: one-pass pack + ballot-bin (scheduled FIRST) ----
    const int bid = blockIdx.x;                  // 0..255
    const int w = t >> 6;
    const int dslice  = bid >> 2;
    const int quarter = bid & 3;
    const int sc      = quarter * 4 + w;
    const int d0      = dslice * SLICE + sc * SC_D;
    unsigned* regw = reg + ((size_t)(dslice * NSC + sc) * NBIN) * BCAP;
    const unsigned long long lmask = (1ull << lane) - 1ull;

    unsigned cb[16];
    #pragma unroll
    for (int b = 0; b < 16; ++b) cb[b] = 0;

    #pragma unroll
    for (int step = 0; step < SC_D / 64; ++step) {
        const int dli = step * 64 + lane;
        const int4 iv = reinterpret_cast<const int4*>(idx)[d0 + dli];
        const int4 sv = reinterpret_cast<const int4*>(sgn)[d0 + dli];
        const unsigned rowbyte = (unsigned)((sc * SC_D + dli) << 7);
        #pragma unroll
        for (int c = 0; c < 4; ++c) {
            const unsigned p = ((unsigned)((c==0)?iv.x:(c==1)?iv.y:(c==2)?iv.z:iv.w)) & 4095u;
            const unsigned s = ((unsigned)((c==0)?sv.x:(c==1)?sv.y:(c==2)?sv.z:sv.w)) & 1u;
            const unsigned e = rowbyte | ((p & 255u) << 19) | ((s ^ 1u) << 31);
            const unsigned bin = p >> 8;
            unsigned pos = 0;
            #pragma unroll
            for (int b = 0; b < 16; ++b) {
                const unsigned long long m = __ballot(bin == (unsigned)b);
                if (bin == (unsigned)b) pos = cb[b] + (unsigned)__popcll(m & lmask);
                cb[b] += (unsigned)__popcll(m);
            }
            if (pos < (unsigned)BCAP) regw[bin * BCAP + pos] = e;
        }
    }
    unsigned cval = 0;
    #pragma unroll
    for (int b = 0; b < 16; ++b) {
        const unsigned cc = cb[b] < (unsigned)BCAP ? cb[b] : (unsigned)BCAP;
        cval = (lane == b) ? cc : cval;
    }
    if (lane < 16) cnt[(dslice * NSC + sc) * NBIN + lane] = (int)cval;
}

// ---------------- K3: two-phase re-bin + scalar-guarded batch-8 process ----
__global__ __launch_bounds__(512, 8) void k_process(
    const unsigned* __restrict__ reg, const int* __restrict__ cnt,
    const unsigned short* __restrict__ xTh, __half* __restrict__ part) {
    __shared__ __half2 hist[WPB][2 * PR_W * 32];   // [w][side*512 + po*32 + word] 32 KB
    __shared__ unsigned lst[WPB][LCAP];            // contiguous per-target lists 4 KB
    __shared__ int cnts[WPB][WPB];                 // [scanwave][target]
    __shared__ int baseL[WPB][WPB];                // [target][scanwave]
    __shared__ int totals[WPB];

    const int w = threadIdx.x >> 6, lane = threadIdx.x & 63;
    const int dslice = blockIdx.x & 63;   // stride-64 peers share xTh slice/XCD
    const int hb  = blockIdx.x >> 6;      // 0..31
    const int bin = hb >> 1, half = hb & 1;

    __half2* hw = hist[w];
    {
        unsigned* h32 = reinterpret_cast<unsigned*>(hw);
        #pragma unroll
        for (int k = 0; k < 16; ++k) h32[k * 64 + lane] = 0u;
    }

    const unsigned long long lmask = (1ull << lane) - 1ull;

    // --- phase 1: count per (scanwave, target); stash entries in regs ---
    unsigned er[4];
    int n0 = 0, n1 = 0;
    int c0 = 0, c1 = 0, c2 = 0, c3 = 0, c4 = 0, c5 = 0, c6 = 0, c7 = 0;
    #pragma unroll
    for (int sc2 = 0; sc2 < 2; ++sc2) {
        const int sc = 2 * w + sc2;
        const int n  = cnt[(dslice * NSC + sc) * NBIN + bin];
        const unsigned* list = reg + ((size_t)((dslice * NSC + sc) * NBIN + bin)) * BCAP;
        if (sc2 == 0) n0 = n; else n1 = n;
        #pragma unroll
        for (int b = 0; b < 2; ++b) {
            const int i = b * 64 + lane;
            const unsigned e = (i < n) ? list[i] : 0u;
            er[sc2 * 2 + b] = e;
            const unsigned po8 = (e >> 19) & 255u;
            const bool valid = (i < n) && ((int)(po8 >> 7) == half);
            const unsigned t = valid ? ((po8 >> 4) & 7u) : 0xFFu;
            c0 += __popcll(__ballot(t == 0u)); c1 += __popcll(__ballot(t == 1u));
            c2 += __popcll(__ballot(t == 2u)); c3 += __popcll(__ballot(t == 3u));
            c4 += __popcll(__ballot(t == 4u)); c5 += __popcll(__ballot(t == 5u));
            c6 += __popcll(__ballot(t == 6u)); c7 += __popcll(__ballot(t == 7u));
        }
    }
    {
        int cval = 0;
        cval = (lane == 0) ? c0 : cval; cval = (lane == 1) ? c1 : cval;
        cval = (lane == 2) ? c2 : cval; cval = (lane == 3) ? c3 : cval;
        cval = (lane == 4) ? c4 : cval; cval = (lane == 5) ? c5 : cval;
        cval = (lane == 6) ? c6 : cval; cval = (lane == 7) ? c7 : cval;
        if (lane < 8) cnts[w][lane] = cval;
    }
    __syncthreads();

    if (w == 0 && lane < 8) {     // lane = target t
        int run = 0;
        #pragma unroll
        for (int ww = 0; ww < 8; ++ww) { baseL[lane][ww] = run; run += cnts[ww][lane]; }
        totals[lane] = run;
    }
    __syncthreads();

    // --- phase 2: re-ballot from regs, write contiguous target lists ---
    c0 = c1 = c2 = c3 = c4 = c5 = c6 = c7 = 0;
    #pragma unroll
    for (int sc2 = 0; sc2 < 2; ++sc2) {
        const int n = (sc2 == 0) ? n0 : n1;
        #pragma unroll
        for (int b = 0; b < 2; ++b) {
            const int i = b * 64 + lane;
            const unsigned e = er[sc2 * 2 + b];
            const unsigned po8 = (e >> 19) & 255u;
            const bool valid = (i < n) && ((int)(po8 >> 7) == half);
            const unsigned t = valid ? ((po8 >> 4) & 7u) : 0xFFu;
            const unsigned long long m0 = __ballot(t == 0u);
            const unsigned long long m1 = __ballot(t == 1u);
            const unsigned long long m2 = __ballot(t == 2u);
            const unsigned long long m3 = __ballot(t == 3u);
            const unsigned long long m4 = __ballot(t == 4u);
            const unsigned long long m5 = __ballot(t == 5u);
            const unsigned long long m6 = __ballot(t == 6u);
            const unsigned long long m7 = __ballot(t == 7u);
            if (valid) {
                const unsigned long long mt =
                    t < 4u ? (t < 2u ? (t == 0u ? m0 : m1) : (t == 2u ? m2 : m3))
                           : (t < 6u ? (t == 4u ? m4 : m5) : (t == 6u ? m6 : m7));
                const int cbase =
                    t < 4u ? (t < 2u ? (t == 0u ? c0 : c1) : (t == 2u ? c2 : c3))
                           : (t < 6u ? (t == 4u ? c4 : c5) : (t == 6u ? c6 : c7));
                const int pos = baseL[t][w] + cbase + (int)__popcll(mt & lmask);
                if (pos < LCAP) lst[t][pos] = e;
            }
            c0 += __popcll(m0); c1 += __popcll(m1);
            c2 += __popcll(m2); c3 += __popcll(m3);
            c4 += __popcll(m4); c5 += __popcll(m5);
            c6 += __popcll(m6); c7 += __popcll(m7);
        }
    }
    __syncthreads();

    // --- process: wave w consumes lst[w]; batches of 8, scalar dup-guard ---
    const char* xs_c = reinterpret_cast<const char*>(xTh) + (size_t)dslice * SLICE * 128;
    const unsigned li4 = (unsigned)(lane & 31) * 4u;
    const bool hi = lane >= 32;
    const unsigned l31 = (unsigned)(lane & 31);
    const int n = totals[w] < LCAP ? totals[w] : LCAP;
    const unsigned* L = lst[w];

    int i = 0;
    for (; i + 8 <= n; i += 8) {
        const uint4 A  = *reinterpret_cast<const uint4*>(L + i);
        const uint4 Bv = *reinterpret_cast<const uint4*>(L + i + 4);
        const unsigned e0 = __builtin_amdgcn_readfirstlane(A.x);
        const unsigned e1 = __builtin_amdgcn_readfirstlane(A.y);
        const unsigned e2 = __builtin_amdgcn_readfirstlane(A.z);
        const unsigned e3 = __builtin_amdgcn_readfirstlane(A.w);
        const unsigned e4 = __builtin_amdgcn_readfirstlane(Bv.x);
        const unsigned e5 = __builtin_amdgcn_readfirstlane(Bv.y);
        const unsigned e6 = __builtin_amdgcn_readfirstlane(Bv.z);
        const unsigned e7 = __builtin_amdgcn_readfirstlane(Bv.w);
        // entries 0-3 -> lo-half lanes, 4-7 -> hi-half lanes
        const unsigned va0 = (hi ? (e4 & 0x7FFFFu) : (e0 & 0x7FFFFu)) + li4;
        const unsigned va1 = (hi ? (e5 & 0x7FFFFu) : (e1 & 0x7FFFFu)) + li4;
        const unsigned va2 = (hi ? (e6 & 0x7FFFFu) : (e2 & 0x7FFFFu)) + li4;
        const unsigned va3 = (hi ? (e7 & 0x7FFFFu) : (e3 & 0x7FFFFu)) + li4;
        const unsigned d0 = *reinterpret_cast<const unsigned*>(xs_c + va0);
        const unsigned d1 = *reinterpret_cast<const unsigned*>(xs_c + va1);
        const unsigned d2 = *reinterpret_cast<const unsigned*>(xs_c + va2);
        const unsigned d3 = *reinterpret_cast<const unsigned*>(xs_c + va3);

        const unsigned pL0 = (e0 >> 19) & 15u, pL1 = (e1 >> 19) & 15u;
        const unsigned pL2 = (e2 >> 19) & 15u, pL3 = (e3 >> 19) & 15u;
        const unsigned pH0 = (e4 >> 19) & 15u, pH1 = (e5 >> 19) & 15u;
        const unsigned pH2 = (e6 >> 19) & 15u, pH3 = (e7 >> 19) & 15u;

        // f16 data: value = gathered dword XOR per-side sign mask (no cvt)
        __half2 v[4];
        #pragma unroll
        for (int k = 0; k < 4; ++k) {
            const unsigned dv = (k == 0) ? d0 : (k == 1) ? d1 : (k == 2) ? d2 : d3;
            const unsigned eL = (k == 0) ? e0 : (k == 1) ? e1 : (k == 2) ? e2 : e3;
            const unsigned eH = (k == 0) ? e4 : (k == 1) ? e5 : (k == 2) ? e6 : e7;
            const unsigned sm = hi ? (eH & 0x80000000u) : (eL & 0x80000000u);
            v[k] = __builtin_bit_cast(__half2, dv ^ (sm ? 0x80008000u : 0u));
        }

        const unsigned a0 = (hi ? (512u + pH0 * 32u) : (pL0 * 32u)) + l31;
        const unsigned a1 = (hi ? (512u + pH1 * 32u) : (pL1 * 32u)) + l31;
        const unsigned a2 = (hi ? (512u + pH2 * 32u) : (pL2 * 32u)) + l31;
        const unsigned a3 = (hi ? (512u + pH3 * 32u) : (pL3 * 32u)) + l31;

        // wave-uniform scalar dup check (po's are SGPRs via readfirstlane)
        const bool dupL = (pL0 == pL1) | (pL0 == pL2) | (pL0 == pL3)
                        | (pL1 == pL2) | (pL1 == pL3) | (pL2 == pL3);
        const bool dupH = (pH0 == pH1) | (pH0 == pH2) | (pH0 == pH3)
                        | (pH1 == pH2) | (pH1 == pH3) | (pH2 == pH3);
        if (!(dupL | dupH)) {
            // fast path: addresses distinct per side -> read-all / write-all
            const __half2 h0 = hw[a0];
            const __half2 h1 = hw[a1];
            const __half2 h2v = hw[a2];
            const __half2 h3 = hw[a3];
            hw[a0] = __hadd2(h0, v[0]);
            hw[a1] = __hadd2(h1, v[1]);
            hw[a2] = __hadd2(h2v, v[2]);
            hw[a3] = __hadd2(h3, v[3]);
        } else {
            // slow path (~17%): sequential RMWs, correct under any dups
            hw[a0] = __hadd2(hw[a0], v[0]);
            hw[a1] = __hadd2(hw[a1], v[1]);
            hw[a2] = __hadd2(hw[a2], v[2]);
            hw[a3] = __hadd2(hw[a3], v[3]);
        }
    }
    for (; i + 2 <= n; i += 2) {    // pair tail: lo/hi sides disjoint -> safe
        const unsigned eA = __builtin_amdgcn_readfirstlane(L[i]);
        const unsigned eB = __builtin_amdgcn_readfirstlane(L[i + 1]);
        const unsigned va = (hi ? (eB & 0x7FFFFu) : (eA & 0x7FFFFu)) + li4;
        const unsigned dv = *reinterpret_cast<const unsigned*>(xs_c + va);
        const unsigned sm = hi ? (eB & 0x80000000u) : (eA & 0x80000000u);
        const unsigned pkb = dv ^ (sm ? 0x80008000u : 0u);
        const unsigned po = hi ? ((eB >> 19) & 15u) : ((eA >> 19) & 15u);
        const unsigned a = (hi ? (512u + po * 32u) : (po * 32u)) + l31;
        hw[a] = __hadd2(hw[a], __builtin_bit_cast(__half2, pkb));
    }
    if (i < n) {                    // odd tail: lo half only
        const unsigned eA = __builtin_amdgcn_readfirstlane(L[i]);
        if (!hi) {
            const unsigned va = (eA & 0x7FFFFu) + li4;
            const unsigned dv = *reinterpret_cast<const unsigned*>(xs_c + va);
            const unsigned pkb = dv ^ ((eA & 0x80000000u) ? 0x80008000u : 0u);
            const unsigned a = ((eA >> 19) & 15u) * 32u + l31;
            hw[a] = __hadd2(hw[a], __builtin_bit_cast(__half2, pkb));
        }
    }

    // writeout: merge LO+HI, store to part (pr = hb*8 + w)
    unsigned* wp32 = reinterpret_cast<unsigned*>(
        part + ((size_t)((hb * WPB + w) * NDS + dslice)) * (PR_W * B_DIM));
    #pragma unroll
    for (int k = 0; k < 8; ++k) {
        const int idxw = k * 64 + lane;            // 0..511
        const __half2 s = __hadd2(hw[idxw], hw[512 + idxw]);
        wp32[idxw] = __builtin_bit_cast(unsigned, s);
    }
}

// ---------------- K4: reduce partials -> out (NPR=256) ----------------
__global__ __launch_bounds__(256) void k_reduce(
    const __half* __restrict__ part, float* __restrict__ out) {
    const int pr = blockIdx.x;       // p-range 0..255 (16 wide)
    const int t  = threadIdx.x;

    float4 acc = make_float4(0.f, 0.f, 0.f, 0.f);
    const size_t base = (size_t)pr * NDS * (PR_W * B_DIM);
    for (int ds = 0; ds < NDS; ++ds) {
        const uint2 pv = *reinterpret_cast<const uint2*>(
            part + base + (size_t)ds * (PR_W * B_DIM) + t * 4);
        const __half2 h0 = __builtin_bit_cast(__half2, pv.x);
        const __half2 h1 = __builtin_bit_cast(__half2, pv.y);
        acc.x += __half2float(h0.x); acc.y += __half2float(h0.y);
        acc.z += __half2float(h1.x); acc.w += __half2float(h1.y);
    }

    __shared__ float st[16][65];
    const int po = (t * 4) >> 6;          // 0..15
    const int b0 = (t * 4) & 63;
    st[po][b0]     = acc.x; st[po][b0 + 1] = acc.y;
    st[po][b0 + 2] = acc.z; st[po][b0 + 3] = acc.w;
    __syncthreads();

    #pragma unroll
    for (int k = 0; k < 4; ++k) {
        const int flat = k * 256 + t;     // b*16 + po
        const int b = flat >> 4, poo = flat & 15;
        out[(size_t)b * P_DIM + pr * PR_W + poo] = st[poo][b];
    }
}

// ---------------- fallback: LDS-atomic histogram ----------------
__device__ __forceinline__ float signed_val(float x, int s) {
    return __uint_as_float(__float_as_uint(x) ^ (((unsigned)(s ^ 1)) << 31));
}

__global__ __launch_bounds__(1024) void sjlt_hist_fb(
    const float* __restrict__ x, const int* __restrict__ idx,
    const int* __restrict__ sgn, float* __restrict__ out) {
    __shared__ float hist[2][P_DIM];
    for (int i = threadIdx.x; i < 2 * P_DIM; i += 1024) (&hist[0][0])[i] = 0.0f;
    __syncthreads();
    const int chunk = blockIdx.x, bg = blockIdx.y;
    const int d0 = chunk * (D_DIM / 16), b0 = bg * 2;
    const float* xr0 = x + (size_t)b0 * D_DIM + d0;
    const float* xr1 = xr0 + D_DIM;
    const int4* iv4 = reinterpret_cast<const int4*>(idx) + d0;
    const int4* sv4 = reinterpret_cast<const int4*>(sgn) + d0;
    for (int t = threadIdx.x; t < D_DIM / 16; t += 1024) {
        const int4 iv = iv4[t]; const int4 sv = sv4[t];
        const float x0 = xr0[t], x1 = xr1[t];
        unsafeAtomicAdd(&hist[0][iv.x], signed_val(x0, sv.x));
        unsafeAtomicAdd(&hist[0][iv.y], signed_val(x0, sv.y));
        unsafeAtomicAdd(&hist[0][iv.z], signed_val(x0, sv.z));
        unsafeAtomicAdd(&hist[0][iv.w], signed_val(x0, sv.w));
        unsafeAtomicAdd(&hist[1][iv.x], signed_val(x1, sv.x));
        unsafeAtomicAdd(&hist[1][iv.y], signed_val(x1, sv.y));
        unsafeAtomicAdd(&hist[1][iv.z], signed_val(x1, sv.z));
        unsafeAtomicAdd(&hist[1][iv.w], signed_val(x1, sv.w));
    }
    __syncthreads();
    float* o = out + (size_t)b0 * P_DIM;
    for (int p = threadIdx.x; p < P_DIM; p += 1024) {
        unsafeAtomicAdd(&o[p],         hist[0][p]);
        unsafeAtomicAdd(&o[P_DIM + p], hist[1][p]);
    }
}

extern "C" void kernel_launch(void* const* d_in, const int* in_sizes, int n_in,
                              void* d_out, int out_size, void* d_ws, size_t ws_size,
                              hipStream_t stream) {
    const float* x   = (const float*)d_in[0];
    const int*   idx = (const int*)d_in[1];
    const int*   sgn = (const int*)d_in[2];
    float* out = (float*)d_out;

    if (ws_size >= WS_NEED) {
        char* ws = (char*)d_ws;
        unsigned* reg = (unsigned*)(ws + REG_OFF);
        int* cnt      = (int*)(ws + CNT_OFF);
        unsigned short* xTh = (unsigned short*)(ws + XT_OFF);
        __half* part  = (__half*)(ws + PART_OFF);

        k_prep<<<TRANS_BLOCKS + BINPK_BLOCKS, 256, 0, stream>>>(x, idx, sgn, xTh, reg, cnt);
        k_process<<<NHB * NDS, 512, 0, stream>>>(reg, cnt, xTh, part);
        k_reduce<<<NPR, 256, 0, stream>>>(part, out);
    } else {
        hipMemsetAsync(d_out, 0, (size_t)out_size * sizeof(float), stream);
        dim3 grid(16, 32);
        sjlt_hist_fb<<<grid, 1024, 0, stream>>>(x, idx, sgn, out);
    }
}